// Round 2
// baseline (573.445 us; speedup 1.0000x reference)
//
#include <hip/hip_runtime.h>
#include <cstdint>
#include <cstddef>

#define NNODES 50000
#define NEDGES 800000
#define NGR    64
#define INDIM  128
#define HIDD   64

typedef __attribute__((ext_vector_type(8))) _Float16 f16x8;
typedef __attribute__((ext_vector_type(2))) _Float16 half2v;
typedef __attribute__((ext_vector_type(4))) float f32x4;

__device__ __forceinline__ float lrelu(float x) { return x > 0.f ? x : 0.2f * x; }
__device__ __forceinline__ float eluf(float x)  { return x > 0.f ? x : expm1f(x); }
__device__ __forceinline__ unsigned short f2h(float x) {   // RNE via v_cvt_f16_f32
    _Float16 h = (_Float16)x;
    return __builtin_bit_cast(unsigned short, h);
}
// fp16 lo/hi of a dword -> f32. Written as fpext(f16) so the fma-mix combine
// can fold the convert into v_fma_mix_f32 at the fmaf use sites.
__device__ __forceinline__ float h2lo(unsigned int u) {
    half2v h = __builtin_bit_cast(half2v, u);
    return (float)h.x;
}
__device__ __forceinline__ float h2hi(unsigned int u) {
    half2v h = __builtin_bit_cast(half2v, u);
    return (float)h.y;
}

// weighted accumulate of 8 fp16 channels (one uint4 dword-pair half) into f32
__device__ __forceinline__ void acc8(uint4 u, float we, float* a) {
    a[0] = fmaf(h2lo(u.x), we, a[0]); a[1] = fmaf(h2hi(u.x), we, a[1]);
    a[2] = fmaf(h2lo(u.y), we, a[2]); a[3] = fmaf(h2hi(u.y), we, a[3]);
    a[4] = fmaf(h2lo(u.z), we, a[4]); a[5] = fmaf(h2hi(u.z), we, a[5]);
    a[6] = fmaf(h2lo(u.w), we, a[6]); a[7] = fmaf(h2hi(u.w), we, a[7]);
}

// ---------------------------------------------------------------------------
// fp32 -> fp16 (weight matrices only)
// ---------------------------------------------------------------------------
__global__ void cvt_f2h(const float* __restrict__ in, unsigned short* __restrict__ out, int n4) {
    int i = blockIdx.x * 256 + threadIdx.x;
    if (i < n4) {
        float4 v = ((const float4*)in)[i];
        ushort4 o;
        o.x = f2h(v.x); o.y = f2h(v.y); o.z = f2h(v.z); o.w = f2h(v.w);
        ((ushort4*)out)[i] = o;
    }
}

// ---------------------------------------------------------------------------
// CSR build (both graphs batched via blockIdx.y). int64 inputs arrive int32.
// ---------------------------------------------------------------------------
__global__ void count_dst(const int* __restrict__ ei0, const int* __restrict__ ei1,
                          int* __restrict__ cnt, int E, int N) {
    const int* ei = blockIdx.y ? ei1 : ei0;
    int* c = cnt + blockIdx.y * N;
    int e = blockIdx.x * 256 + threadIdx.x;
    if (e < E) atomicAdd(&c[ei[E + e]], 1);
}

__global__ __launch_bounds__(256) void scan_part(const int* __restrict__ cnt,
                                                 int* __restrict__ psum, int n) {
    __shared__ int ws[4];
    const int* c = cnt + blockIdx.y * n;
    int* p = psum + blockIdx.y * 256;
    int lane = threadIdx.x & 63, w = threadIdx.x >> 6;
    int i = blockIdx.x * 256 + threadIdx.x;
    int v = (i < n) ? c[i] : 0;
    #pragma unroll
    for (int off = 32; off >= 1; off >>= 1) v += __shfl_xor(v, off, 64);
    if (lane == 0) ws[w] = v;
    __syncthreads();
    if (threadIdx.x == 0) p[blockIdx.x] = ws[0] + ws[1] + ws[2] + ws[3];
}

__global__ __launch_bounds__(256) void scan_tops(int* __restrict__ psum,
                                                 int* __restrict__ rp, int nb, int n) {
    __shared__ int wsum[4];
    int* p = psum + blockIdx.x * 256;
    int* r = rp + blockIdx.x * (n + 1);
    int tid = threadIdx.x, lane = tid & 63, w = tid >> 6;
    int v = (tid < nb) ? p[tid] : 0;
    int x = v;
    #pragma unroll
    for (int off = 1; off < 64; off <<= 1) {
        int t = __shfl_up(x, off, 64);
        if (lane >= off) x += t;
    }
    if (lane == 63) wsum[w] = x;
    __syncthreads();
    int add = 0;
    for (int k = 0; k < w; k++) add += wsum[k];
    int incl = x + add;
    if (tid < nb) p[tid] = incl - v;
    if (tid == nb - 1) r[n] = incl;
}

__global__ __launch_bounds__(256) void scan_fin(const int* __restrict__ cnt,
                                                const int* __restrict__ psum,
                                                int* __restrict__ rp, int n) {
    __shared__ int wsum[4];
    const int* c = cnt + blockIdx.y * n;
    const int* p = psum + blockIdx.y * 256;
    int* r = rp + blockIdx.y * (n + 1);
    int tid = threadIdx.x, lane = tid & 63, w = tid >> 6;
    int i = blockIdx.x * 256 + tid;
    int v = (i < n) ? c[i] : 0;
    int x = v;
    #pragma unroll
    for (int off = 1; off < 64; off <<= 1) {
        int t = __shfl_up(x, off, 64);
        if (lane >= off) x += t;
    }
    if (lane == 63) wsum[w] = x;
    __syncthreads();
    int add = p[blockIdx.x];
    for (int k = 0; k < w; k++) add += wsum[k];
    if (i < n) r[i] = x + add - v;
}

__global__ void fill_csr(const int* __restrict__ ei0, const int* __restrict__ ei1,
                         const int* __restrict__ rp, int* __restrict__ fc,
                         int* __restrict__ col, int E, int N) {
    int g = blockIdx.y;
    const int* ei = g ? ei1 : ei0;
    const int* r = rp + g * (N + 1);
    int* f = fc + g * N;
    int* cl = col + (size_t)g * E;
    int e = blockIdx.x * 256 + threadIdx.x;
    if (e < E) {
        int s = ei[e];
        int d = ei[E + e];
        int pos = atomicAdd(&f[d], 1);
        cl[r[d] + pos] = s;
    }
}

// ---------------------------------------------------------------------------
// MFMA fp16 GEMM with fused alpha epilogue.
// ---------------------------------------------------------------------------
template<int BN, int WM, int WN, bool AF32>
__global__ __launch_bounds__(256) void gemm_mfma(const void* __restrict__ A0,
                                                 const void* __restrict__ A1,
                                                 size_t Ags,
                                                 const unsigned short* __restrict__ Bw,
                                                 unsigned short* __restrict__ C,
                                                 size_t Cgs,
                                                 int M, int K, int N,
                                                 const float* __restrict__ a_src,
                                                 const float* __restrict__ a_dst,
                                                 float* __restrict__ as_o,
                                                 float* __restrict__ ad_o,
                                                 int hstride, int ags) {
    constexpr int BM = 128, BK = 64;
    constexpr int MI = WM / 16, NI = WN / 16;
    constexpr int LDA = BK + 8;
    __shared__ unsigned short Asm[BM * LDA];
    __shared__ unsigned short Bsm[BN * LDA];
    int gph = blockIdx.z;
    const float* Af = (const float*)(gph ? A1 : A0);
    const unsigned short* Ab = (const unsigned short*)A0 + (size_t)gph * Ags;
    unsigned short* Cg = C + (size_t)gph * Cgs;
    float* aso = as_o + (size_t)gph * ags;
    float* ado = ad_o + (size_t)gph * ags;
    int tid = threadIdx.x;
    int lane = tid & 63, wave = tid >> 6;
    int l15 = lane & 15, quad = lane >> 4;
    int wm0, wn0;
    if (BN == 128) { wm0 = (wave >> 1) * 64; wn0 = (wave & 1) * 64; }
    else           { wm0 = wave * 32;        wn0 = 0; }
    int row0 = blockIdx.x * BM;
    int c0 = blockIdx.y * BN;

    f32x4 acc[MI][NI];
    #pragma unroll
    for (int mi = 0; mi < MI; mi++)
        #pragma unroll
        for (int ni = 0; ni < NI; ni++)
            acc[mi][ni] = (f32x4){0.f, 0.f, 0.f, 0.f};

    for (int k0 = 0; k0 < K; k0 += BK) {
        #pragma unroll
        for (int q = 0; q < BM / 32; q++) {
            int idx = q * 256 + tid;
            int r = idx >> 3, kc = idx & 7;
            int row = row0 + r;
            if (AF32) {
                float4 v0 = make_float4(0.f, 0.f, 0.f, 0.f), v1 = v0;
                if (row < M) {
                    v0 = *(const float4*)(Af + (size_t)row * K + k0 + kc * 8);
                    v1 = *(const float4*)(Af + (size_t)row * K + k0 + kc * 8 + 4);
                }
                unsigned short t[8] = {f2h(v0.x), f2h(v0.y), f2h(v0.z), f2h(v0.w),
                                       f2h(v1.x), f2h(v1.y), f2h(v1.z), f2h(v1.w)};
                *(uint4*)&Asm[r * LDA + kc * 8] = *(uint4*)t;
            } else {
                uint4 v = make_uint4(0u, 0u, 0u, 0u);
                if (row < M) v = *(const uint4*)(Ab + (size_t)row * K + k0 + kc * 8);
                *(uint4*)&Asm[r * LDA + kc * 8] = v;
            }
        }
        #pragma unroll
        for (int q = 0; q < BN / 32; q++) {
            int idx = q * 256 + tid;
            int n  = idx & (BN - 1);
            int kc = idx / BN;
            unsigned short tmp[8];
            #pragma unroll
            for (int j = 0; j < 8; j++)
                tmp[j] = Bw[(size_t)(k0 + kc * 8 + j) * N + c0 + n];
            *(uint4*)&Bsm[n * LDA + kc * 8] = *(uint4*)tmp;
        }
        __syncthreads();
        #pragma unroll
        for (int kb = 0; kb < 2; kb++) {
            f16x8 af[MI], bfr[NI];
            #pragma unroll
            for (int mi = 0; mi < MI; mi++)
                af[mi] = *(f16x8*)&Asm[(wm0 + mi * 16 + l15) * LDA + kb * 32 + quad * 8];
            #pragma unroll
            for (int ni = 0; ni < NI; ni++)
                bfr[ni] = *(f16x8*)&Bsm[(wn0 + ni * 16 + l15) * LDA + kb * 32 + quad * 8];
            #pragma unroll
            for (int mi = 0; mi < MI; mi++)
                #pragma unroll
                for (int ni = 0; ni < NI; ni++)
                    acc[mi][ni] = __builtin_amdgcn_mfma_f32_16x16x32_f16(
                        af[mi], bfr[ni], acc[mi][ni], 0, 0, 0);
        }
        __syncthreads();
    }
    #pragma unroll
    for (int mi = 0; mi < MI; mi++) {
        #pragma unroll
        for (int r = 0; r < 4; r++) {
            int row = row0 + wm0 + mi * 16 + quad * 4 + r;
            if (row < M) {
                #pragma unroll
                for (int ni = 0; ni < NI; ni++) {
                    int colg = c0 + wn0 + ni * 16 + l15;
                    Cg[(size_t)row * N + colg] = f2h(acc[mi][ni][r]);
                }
            }
        }
    }
    int headc = (c0 + wn0) >> 6;
    float a_s[NI], a_d[NI];
    #pragma unroll
    for (int ni = 0; ni < NI; ni++) {
        a_s[ni] = a_src[headc * 64 + ni * 16 + l15];
        a_d[ni] = a_dst[headc * 64 + ni * 16 + l15];
    }
    #pragma unroll
    for (int mi = 0; mi < MI; mi++) {
        #pragma unroll
        for (int r = 0; r < 4; r++) {
            float ps = 0.f, pd = 0.f;
            #pragma unroll
            for (int ni = 0; ni < NI; ni++) {
                ps += acc[mi][ni][r] * a_s[ni];
                pd += acc[mi][ni][r] * a_d[ni];
            }
            #pragma unroll
            for (int off = 1; off < 16; off <<= 1) {
                ps += __shfl_xor(ps, off, 64);
                pd += __shfl_xor(pd, off, 64);
            }
            int row = row0 + wm0 + mi * 16 + quad * 4 + r;
            if (l15 == 0 && row < M) {
                aso[row * hstride + headc] = ps;
                ado[row * hstride + headc] = pd;
            }
        }
    }
}

// ---------------------------------------------------------------------------
// GAT aggregation, 4 heads x 64 dim, one wave per dst node.
// 4 edges in flight (lane = 16*p + c, c covers uint4 pair {2c,2c+1} ->
// channels [16c,16c+16), headc = c>>2), software-pipelined one quad deep,
// next j-block's colv/as gather prefetched under the current block's work.
// h is fp16; accumulate via fmaf(fpext(f16),w,acc) -> v_fma_mix_f32.
// ---------------------------------------------------------------------------
__global__ __launch_bounds__(256) void agg_h4(const unsigned short* __restrict__ h,
                                              size_t hgs,
                                              const float* __restrict__ as_,
                                              const float* __restrict__ ad_, int ags,
                                              const int* __restrict__ rp,
                                              const int* __restrict__ col,
                                              const float* __restrict__ bias,
                                              unsigned short* __restrict__ out,
                                              size_t ogs, int n, int E) {
    int gph = blockIdx.y;
    const uint4* h4 = (const uint4*)(h + (size_t)gph * hgs);   // 32 uint4 per row
    const float* as = as_ + (size_t)gph * ags;
    const float* adp = ad_ + (size_t)gph * ags;
    const int* r = rp + gph * (n + 1);
    const int* cl = col + (size_t)gph * E;
    unsigned short* og = out + (size_t)gph * ogs;

    int wave = threadIdx.x >> 6, lane = threadIdx.x & 63;
    int node = blockIdx.x * 4 + wave;
    if (node >= n) return;
    int p = lane >> 4;            // edge slot within quad (0..3); == loader head
    int c = lane & 15;            // uint4-pair index -> channels [16c,16c+16)
    int headc = c >> 2;           // this lane's channel head
    float adv_q = adp[node * 4 + p];         // loader's head adv
    // self loop (counted once, on p==0 group)
    float w0 = __expf(lrelu(as[node * 4 + headc] + adp[node * 4 + headc]));
    float m0 = (p == 0) ? w0 : 0.f;
    uint4 hu0 = h4[(size_t)node * 32 + 2 * c];
    uint4 hu1 = h4[(size_t)node * 32 + 2 * c + 1];
    float den = m0;
    float a[16] = {0.f, 0.f, 0.f, 0.f, 0.f, 0.f, 0.f, 0.f,
                   0.f, 0.f, 0.f, 0.f, 0.f, 0.f, 0.f, 0.f};
    acc8(hu0, m0, a);
    acc8(hu1, m0, a + 8);
    int beg = __builtin_amdgcn_readfirstlane(r[node]);
    int end = __builtin_amdgcn_readfirstlane(r[node + 1]);
    int hbase = headc << 4;
    int j = beg;
    int m = end - j; if (m > 16) m = 16;
    int colv = 0; float asv = 0.f;
    if (j < end) {
        colv = cl[j + (c < m ? c : m - 1)];
        asv = as[colv * 4 + p];
    }
    while (j < end) {
        int jn = j + 16;
        int mn = end - jn; if (mn > 16) mn = 16;
        int colv_n = 0; float asv_n = 0.f;
        if (mn > 0) {            // prefetch next block's weight inputs early
            colv_n = cl[jn + (c < mn ? c : mn - 1)];
            asv_n = as[colv_n * 4 + p];
        }
        float wl = __expf(lrelu(asv + adv_q));   // weight(edge c, head p)
        // pipelined quads: next quad's loads in flight during current FMAs
        int e0 = p;
        int ec = e0 < m ? e0 : m - 1;
        float we = __shfl(wl, hbase | ec);
        if (e0 >= m) we = 0.f;
        int s = __shfl(colv, ec);
        uint4 u0 = h4[(size_t)s * 32 + 2 * c];
        uint4 u1 = h4[(size_t)s * 32 + 2 * c + 1];
        for (int base = 4; base < m; base += 4) {
            int e2 = base + p;
            int ec2 = e2 < m ? e2 : m - 1;
            float we2 = __shfl(wl, hbase | ec2);
            if (e2 >= m) we2 = 0.f;
            int s2 = __shfl(colv, ec2);
            uint4 v0 = h4[(size_t)s2 * 32 + 2 * c];
            uint4 v1 = h4[(size_t)s2 * 32 + 2 * c + 1];
            den += we;
            acc8(u0, we, a);
            acc8(u1, we, a + 8);
            we = we2; u0 = v0; u1 = v1;
        }
        den += we;
        acc8(u0, we, a);
        acc8(u1, we, a + 8);
        j = jn; m = mn; colv = colv_n; asv = asv_n;
    }
    // combine the four edge-slot groups (lane^16, lane^32 have same channels)
    #pragma unroll
    for (int off = 16; off < 64; off <<= 1) {
        den += __shfl_xor(den, off);
        #pragma unroll
        for (int k = 0; k < 16; k++) a[k] += __shfl_xor(a[k], off);
    }
    if (p == 0) {   // lanes 0..15, each writes channels [16c,16c+16)
        float rden = 1.f / (den + 1e-16f);
        const float4* b4 = (const float4*)bias;
        unsigned short t[16];
        #pragma unroll
        for (int q = 0; q < 4; q++) {
            float4 bq = b4[c * 4 + q];
            t[4 * q]     = f2h(eluf(a[4 * q]     * rden + bq.x));
            t[4 * q + 1] = f2h(eluf(a[4 * q + 1] * rden + bq.y));
            t[4 * q + 2] = f2h(eluf(a[4 * q + 2] * rden + bq.z));
            t[4 * q + 3] = f2h(eluf(a[4 * q + 3] * rden + bq.w));
        }
        uint4* orow = (uint4*)(og + (size_t)node * 256);
        orow[2 * c]     = *(uint4*)&t[0];
        orow[2 * c + 1] = *(uint4*)&t[8];
    }
}

// ---------------------------------------------------------------------------
// conv2 aggregation: 1 head x 64 dim, one wave per dst node.
// 8 edges in flight: lane = 8*p + c; pipelined one octet deep; next 64-edge
// block's colv/as gather prefetched. h is fp16, fma_mix accumulate.
// ---------------------------------------------------------------------------
__global__ __launch_bounds__(256) void agg_h1(const unsigned short* __restrict__ h,
                                              size_t hgs,
                                              const float* __restrict__ as_,
                                              const float* __restrict__ ad_,
                                              const int* __restrict__ rp,
                                              const int* __restrict__ col,
                                              const float* __restrict__ bias,
                                              float* __restrict__ out,
                                              size_t ogs, int n, int E) {
    int gph = blockIdx.y;
    const uint4* h4 = (const uint4*)(h + (size_t)gph * hgs);   // 8 uint4 per row
    const float* as = as_ + (size_t)gph * n;
    const float* adp = ad_ + (size_t)gph * n;
    const int* r = rp + gph * (n + 1);
    const int* cl = col + (size_t)gph * E;
    float* og = out + (size_t)gph * ogs;

    int wave = threadIdx.x >> 6, lane = threadIdx.x & 63;
    int node = blockIdx.x * 4 + wave;
    if (node >= n) return;
    int p = lane >> 3;            // edge slot within octet
    int c = lane & 7;             // uint4 index in row -> channels [8c,8c+8)
    float adv = adp[node];
    float w0 = __expf(lrelu(as[node] + adv));
    float m0 = (p == 0) ? w0 : 0.f;
    uint4 hu = h4[(size_t)node * 8 + c];
    float den = m0;
    float a[8] = {0.f, 0.f, 0.f, 0.f, 0.f, 0.f, 0.f, 0.f};
    acc8(hu, m0, a);
    int beg = __builtin_amdgcn_readfirstlane(r[node]);
    int end = __builtin_amdgcn_readfirstlane(r[node + 1]);
    int j = beg;
    int m = end - j; if (m > 64) m = 64;
    int colv = 0; float asv = 0.f;
    if (j < end) {
        colv = cl[j + (lane < m ? lane : m - 1)];
        asv = as[colv];
    }
    while (j < end) {
        int jn = j + 64;
        int mn = end - jn; if (mn > 64) mn = 64;
        int colv_n = 0; float asv_n = 0.f;
        if (mn > 0) {            // prefetch next block's weight inputs early
            colv_n = cl[jn + (lane < mn ? lane : mn - 1)];
            asv_n = as[colv_n];
        }
        float wl = __expf(lrelu(asv + adv));
        // pipelined octets
        int e0 = p;
        int ec = e0 < m ? e0 : m - 1;
        float we = __shfl(wl, ec);
        if (e0 >= m) we = 0.f;
        int s = __shfl(colv, ec);
        uint4 u = h4[(size_t)s * 8 + c];
        for (int base = 8; base < m; base += 8) {
            int e2 = base + p;
            int ec2 = e2 < m ? e2 : m - 1;
            float we2 = __shfl(wl, ec2);
            if (e2 >= m) we2 = 0.f;
            int s2 = __shfl(colv, ec2);
            uint4 u2 = h4[(size_t)s2 * 8 + c];
            den += we;
            acc8(u, we, a);
            we = we2; u = u2;
        }
        den += we;
        acc8(u, we, a);
        j = jn; m = mn; colv = colv_n; asv = asv_n;
    }
    #pragma unroll
    for (int off = 8; off < 64; off <<= 1) {
        den += __shfl_xor(den, off);
        #pragma unroll
        for (int k = 0; k < 8; k++) a[k] += __shfl_xor(a[k], off);
    }
    if (p == 0) {
        float rden = 1.f / (den + 1e-16f);
        float4 b0 = ((const float4*)bias)[c * 2];
        float4 b1 = ((const float4*)bias)[c * 2 + 1];
        float4 o0, o1;
        o0.x = eluf(a[0] * rden + b0.x); o0.y = eluf(a[1] * rden + b0.y);
        o0.z = eluf(a[2] * rden + b0.z); o0.w = eluf(a[3] * rden + b0.w);
        o1.x = eluf(a[4] * rden + b1.x); o1.y = eluf(a[5] * rden + b1.y);
        o1.z = eluf(a[6] * rden + b1.z); o1.w = eluf(a[7] * rden + b1.w);
        float* orow = og + (size_t)node * 64 + c * 8;
        *(float4*)orow = o0;
        *(float4*)(orow + 4) = o1;
    }
}

// ---------------------------------------------------------------------------
// Mean pool over SORTED batch ids
// ---------------------------------------------------------------------------
__device__ __forceinline__ int lbound(const int* __restrict__ a, int n, int key) {
    int lo = 0, hi = n;
    while (lo < hi) {
        int mid = (lo + hi) >> 1;
        if (a[mid] < key) lo = mid + 1; else hi = mid;
    }
    return lo;
}

__global__ __launch_bounds__(256) void pool_mean(const float* __restrict__ g2,
                                                 size_t ggs,
                                                 const int* __restrict__ b0,
                                                 const int* __restrict__ b1,
                                                 float* __restrict__ out, int n) {
    __shared__ float red[4][64];
    __shared__ int bnds[2];
    int gph = blockIdx.y;
    const int* batch = gph ? b1 : b0;
    const float* gg = g2 + (size_t)gph * ggs;
    float* og = out + (size_t)gph * NGR * HIDD;
    int g = blockIdx.x;
    if (threadIdx.x < 2) bnds[threadIdx.x] = lbound(batch, n, g + (int)threadIdx.x);
    __syncthreads();
    int s = bnds[0], e = bnds[1];
    int lane = threadIdx.x & 63, wave = threadIdx.x >> 6;
    float acc = 0.f;
    for (int i = s + wave; i < e; i += 4)
        acc += gg[(size_t)i * 64 + lane];
    red[wave][lane] = acc;
    __syncthreads();
    if (wave == 0) {
        float sum = red[0][lane] + red[1][lane] + red[2][lane] + red[3][lane];
        og[g * 64 + lane] = sum / fmaxf((float)(e - s), 1.0f);
    }
}

// ---------------------------------------------------------------------------
extern "C" void kernel_launch(void* const* d_in, const int* in_sizes, int n_in,
                              void* d_out, int out_size, void* d_ws, size_t ws_size,
                              hipStream_t stream) {
    const int N = NNODES, E = NEDGES;

    const float* x1 = (const float*)d_in[0];
    const float* x2 = (const float*)d_in[3];
    const int* ei1v = (const int*)d_in[1];
    const int* ei2v = (const int*)d_in[4];
    const int* ba1  = (const int*)d_in[2];
    const int* ba2  = (const int*)d_in[5];
    const float* W1     = (const float*)d_in[6];
    const float* a_src1 = (const float*)d_in[7];
    const float* a_dst1 = (const float*)d_in[8];
    const float* b1     = (const float*)d_in[9];
    const float* W2     = (const float*)d_in[10];
    const float* a_src2 = (const float*)d_in[11];
    const float* a_dst2 = (const float*)d_in[12];
    const float* b2     = (const float*)d_in[13];

    // Workspace (~125 MB):
    //  R1: h1 fp16 (51.2M) -> g2 fp32 (25.6M)
    //  R2: g1 fp16 (51.2M)
    //  R3: h2 fp16 (12.8M)
    char* ws = (char*)d_ws;
    size_t off = 0;
    auto carve = [&](size_t bytes) -> char* {
        char* p = ws + off;
        off = (off + bytes + 255) & ~(size_t)255;
        return p;
    };
    char* R1 = carve((size_t)2 * N * 256 * 2);
    char* R2 = carve((size_t)2 * N * 256 * 2);
    char* R3 = carve((size_t)2 * N * 64 * 2);
    int*   col  = (int*)carve((size_t)2 * E * 4);
    int*   rp   = (int*)carve((size_t)2 * (N + 1) * 4);
    int*   cntN = (int*)carve((size_t)2 * N * 4);
    int*   psum = (int*)carve(2 * 256 * 4);
    float* as1  = (float*)carve((size_t)2 * N * 4 * 4);
    float* ad1  = (float*)carve((size_t)2 * N * 4 * 4);
    float* as2  = (float*)carve((size_t)2 * N * 4);
    float* ad2  = (float*)carve((size_t)2 * N * 4);
    unsigned short* W1h = (unsigned short*)carve(INDIM * 256 * 2);
    unsigned short* W2h = (unsigned short*)carve(256 * HIDD * 2);

    unsigned short* h1 = (unsigned short*)R1;            // [2][N*256] fp16
    unsigned short* g1 = (unsigned short*)R2;            // [2][N*256] fp16
    unsigned short* h2 = (unsigned short*)R3;            // [2][N*64] fp16
    float* g2 = (float*)R1;                              // [2][N*64] fp32 (after h1 dead)

    float* outF = (float*)d_out;

    const int nodeBlocks = (N + 3) / 4;
    const int nb = (N + 255) / 256;
    const int eb = (E + 255) / 256;

    // weight conversions (tiny)
    cvt_f2h<<<(INDIM * 256 / 4 + 255) / 256, 256, 0, stream>>>(W1, W1h, INDIM * 256 / 4);
    cvt_f2h<<<(256 * HIDD / 4 + 255) / 256, 256, 0, stream>>>(W2, W2h, 256 * HIDD / 4);

    // CSR build
    hipMemsetAsync(cntN, 0, (size_t)2 * N * 4, stream);
    count_dst<<<dim3(eb, 2), 256, 0, stream>>>(ei1v, ei2v, cntN, E, N);
    scan_part<<<dim3(nb, 2), 256, 0, stream>>>(cntN, psum, N);
    scan_tops<<<2, 256, 0, stream>>>(psum, rp, nb, N);
    scan_fin<<<dim3(nb, 2), 256, 0, stream>>>(cntN, psum, rp, N);
    hipMemsetAsync(cntN, 0, (size_t)2 * N * 4, stream);
    fill_csr<<<dim3(eb, 2), 256, 0, stream>>>(ei1v, ei2v, rp, cntN, col, E, N);

    // conv1: h1 = x @ W1 (fp32 A staged in-kernel), alpha fused
    gemm_mfma<128, 64, 64, true><<<dim3(391, 2, 2), 256, 0, stream>>>(
        x1, x2, 0, W1h, h1, (size_t)N * 256, N, INDIM, 256,
        a_src1, a_dst1, as1, ad1, 4, N * 4);
    agg_h4<<<dim3(nodeBlocks, 2), 256, 0, stream>>>(h1, (size_t)N * 256, as1, ad1, N * 4,
                                                    rp, col, b1, g1, (size_t)N * 256, N, E);

    // conv2: h2 = g1 @ W2 (fp16 A), alpha fused
    gemm_mfma<64, 32, 64, false><<<dim3(391, 1, 2), 256, 0, stream>>>(
        g1, nullptr, (size_t)N * 256, W2h, h2, (size_t)N * 64, N, 256, HIDD,
        a_src2, a_dst2, as2, ad2, 1, N);
    agg_h1<<<dim3(nodeBlocks, 2), 256, 0, stream>>>(h2, (size_t)N * 64, as2, ad2,
                                                    rp, col, b2, g2, (size_t)N * 64, N, E);

    // mean pool
    pool_mean<<<dim3(NGR, 2), 256, 0, stream>>>(g2, (size_t)N * 64, ba1, ba2, outF, N);
}